// Round 2
// 383.460 us; speedup vs baseline: 1.0547x; 1.0547x over previous
//
#include <hip/hip_runtime.h>

// ---------- types ----------
typedef __bf16 bf16x8 __attribute__((ext_vector_type(8)));
typedef float f32x4 __attribute__((ext_vector_type(4)));
typedef unsigned short u16x8 __attribute__((ext_vector_type(8)));
typedef unsigned short u16x4 __attribute__((ext_vector_type(4)));

__device__ __forceinline__ unsigned short f2b_u(float f) {
  unsigned int u;
  __builtin_memcpy(&u, &f, 4);
  unsigned int r = 0x7FFFu + ((u >> 16) & 1u);  // round-to-nearest-even
  return (unsigned short)((u + r) >> 16);
}
__device__ __forceinline__ float silu_f(float x) { return x / (1.f + expf(-x)); }

// ---------- fp32 -> bf16 (weights) ----------
__global__ __launch_bounds__(256) void cvt_w(const float* __restrict__ in,
                                             unsigned short* __restrict__ out) {
  int i = (blockIdx.x * 256 + threadIdx.x) * 4;  // grid 256 -> 262144 f32
  f32x4 x = *(const f32x4*)(in + i);
  u16x4 o;
#pragma unroll
  for (int j = 0; j < 4; ++j) o[j] = f2b_u(x[j]);
  *(u16x4*)(out + i) = o;
}

// ---------- rope sin/cos table: TBL[pos][ip] = (sin, cos), pos<8192, ip<32 ----------
__global__ __launch_bounds__(256) void gen_tbl(float* __restrict__ T) {
  int idx = blockIdx.x * 256 + threadIdx.x;  // grid 1024 -> 262144
  int pos = idx >> 5, ip = idx & 31;
  float f = (float)pos * powf(10000.f, -(float)ip * (1.f / 32.f));
  float sn, cs;
  sincosf(f, &sn, &cs);
  T[idx * 2] = sn;
  T[idx * 2 + 1] = cs;
}

// ---------- projection v3: Y = X @ W^T + b ----------
// tile 64m x 256n, block 512 (8 waves, each 64m x 32n), grid 1024 (bid&1 = n-half).
// PROVEN-SAFE loop structure (same as gemm_qtv): single LDS buffer,
//   sync; write LDS; sync; prefetch regs(kt+32); read frags + MFMA.
// Register-direct epilogues (no epilogue LDS, no epilogue barriers):
// MODE 0: QT = T(silu(rope(Y)))          via acc  (r<->seq, direct u16x4 stores)
// MODE 1: VT = T(silu(Y))                via acc  (r<->seq)
//         Kn = silu(rope(Y)) natural     via acc2 = swapped-operand mfma (r<->ch,
//              in-lane rope pairs, direct u16x4 stores) — same LDS fragments.
template <int MODE>
__global__ __launch_bounds__(512, 4) void proj4(
    const float* __restrict__ A, const unsigned short* __restrict__ B,
    unsigned short* __restrict__ Ct, const float* __restrict__ bias,
    unsigned short* __restrict__ Cn, const float* __restrict__ TBL) {
  __shared__ __align__(16) unsigned short sA[64][40];   // 5,120 B
  __shared__ __align__(16) unsigned short sB[256][40];  // 20,480 B

  const int bid = blockIdx.x;
  const int n0 = (bid & 1) << 8;          // 0 or 256
  const long m0 = (long)(bid >> 1) << 6;  // 64-row m-tiles
  const int tid = threadIdx.x;
  const int lane = tid & 63, w = tid >> 6;
  const int wn = w << 5;  // wave n-offset: 0..224
  const int l16 = lane & 15, q8 = (lane >> 4) << 3, rq = (lane >> 4) << 2;
  const int ar = tid >> 3, ac = (tid & 7) << 2;  // A stage: 64x32 f32, coalesced
  const int br = tid >> 1, bc = (tid & 1) << 4;  // B stage: 256x32 bf16

  const float* Ap = A + (m0 + ar) * 512 + ac;
  const unsigned short* Bp = B + (long)(n0 + br) * 512 + bc;

  f32x4 acc[4][2] = {};
  f32x4 acc2[2][4] = {};  // MODE 1 only (DCE'd in MODE 0)

  // prologue: load k-tile 0 into registers
  f32x4 av = *(const f32x4*)Ap;
  u16x8 b0 = *(const u16x8*)Bp;
  u16x8 b1 = *(const u16x8*)(Bp + 8);

  for (int kt = 0; kt < 512; kt += 32) {
    __syncthreads();  // previous iteration's LDS readers are done
    {
      u16x4 a4;
#pragma unroll
      for (int j = 0; j < 4; ++j) a4[j] = f2b_u(av[j]);
      *(u16x4*)&sA[ar][ac] = a4;
      *(u16x8*)&sB[br][bc] = b0;
      *(u16x8*)&sB[br][bc + 8] = b1;
    }
    __syncthreads();  // tile visible to all waves
    if (kt < 480) {   // prefetch next tile into registers, hidden under MFMAs
      av = *(const f32x4*)(Ap + kt + 32);
      b0 = *(const u16x8*)(Bp + kt + 32);
      b1 = *(const u16x8*)(Bp + kt + 40);
    }
    bf16x8 af[4], bf[2];
#pragma unroll
    for (int i = 0; i < 4; ++i) af[i] = *(const bf16x8*)&sA[(i << 4) + l16][q8];
#pragma unroll
    for (int j = 0; j < 2; ++j) bf[j] = *(const bf16x8*)&sB[wn + (j << 4) + l16][q8];
#pragma unroll
    for (int i = 0; i < 4; ++i)
#pragma unroll
      for (int j = 0; j < 2; ++j)
        acc[i][j] = __builtin_amdgcn_mfma_f32_16x16x32_bf16(af[i], bf[j], acc[i][j], 0, 0, 0);
    if (MODE == 1) {
#pragma unroll
      for (int ci = 0; ci < 2; ++ci)
#pragma unroll
        for (int sj = 0; sj < 4; ++sj)
          acc2[ci][sj] =
              __builtin_amdgcn_mfma_f32_16x16x32_bf16(bf[ci], af[sj], acc2[ci][sj], 0, 0, 0);
    }
  }

  const int batch = (int)(m0 >> 13);
  const int s0 = ((int)m0) & 8191;  // rope position base

  // bias for acc (col = ch = l16-indexed)
#pragma unroll
  for (int j = 0; j < 2; ++j) {
    float bv = bias[n0 + wn + (j << 4) + l16];
#pragma unroll
    for (int i = 0; i < 4; ++i)
#pragma unroll
      for (int r = 0; r < 4; ++r) acc[i][j][r] += bv;
  }

  if (MODE == 0) {
    // rope on acc (ch pairs live in adjacent lanes -> shfl_xor 1)
    if (n0 + wn < 64) {
#pragma unroll
      for (int j = 0; j < 2; ++j) {
        int ip = ((wn + (j << 4)) >> 1) + (l16 >> 1);
        float sgn = (l16 & 1) ? 1.f : -1.f;
#pragma unroll
        for (int i = 0; i < 4; ++i)
#pragma unroll
          for (int r = 0; r < 4; ++r) {
            int pos = s0 + (i << 4) + rq + r;
            const float* t = TBL + ((long)pos << 6) + (ip << 1);
            float sn = t[0], cs = t[1];
            float v = acc[i][j][r];
            float p = __shfl_xor(v, 1);
            acc[i][j][r] = v * cs + sgn * sn * p;
          }
      }
    }
  }

  // transposed store (QT in MODE 0, VT in MODE 1): r-run = 4 consecutive seq
  {
    unsigned short* dstT = Ct + ((long)batch << 22);
#pragma unroll
    for (int i = 0; i < 4; ++i)
#pragma unroll
      for (int j = 0; j < 2; ++j) {
        u16x4 o;
#pragma unroll
        for (int r = 0; r < 4; ++r) o[r] = f2b_u(silu_f(acc[i][j][r]));
        *(u16x4*)(dstT + (long)(n0 + wn + (j << 4) + l16) * 8192 + s0 + (i << 4) + rq) = o;
      }
  }

  if (MODE == 1) {
    // acc2: row = ch (rq+r), col = seq (l16)
#pragma unroll
    for (int ci = 0; ci < 2; ++ci) {
      float bv2[4];
#pragma unroll
      for (int r = 0; r < 4; ++r) bv2[r] = bias[n0 + wn + (ci << 4) + rq + r];
#pragma unroll
      for (int sj = 0; sj < 4; ++sj)
#pragma unroll
        for (int r = 0; r < 4; ++r) acc2[ci][sj][r] += bv2[r];
    }
    if (n0 + wn < 64) {  // rope: ch pairs are (r, r+1) within the lane — no shuffle
#pragma unroll
      for (int ci = 0; ci < 2; ++ci)
#pragma unroll
        for (int sj = 0; sj < 4; ++sj) {
          int pos = s0 + (sj << 4) + l16;
          const float* tb = TBL + ((long)pos << 6);
#pragma unroll
          for (int rp = 0; rp < 4; rp += 2) {
            int ip = (wn + (ci << 4) + rq + rp) >> 1;
            float sn = tb[ip << 1], cs = tb[(ip << 1) + 1];
            float v0 = acc2[ci][sj][rp], v1 = acc2[ci][sj][rp + 1];
            acc2[ci][sj][rp] = v0 * cs - sn * v1;
            acc2[ci][sj][rp + 1] = v1 * cs + sn * v0;
          }
        }
    }
    unsigned short* dstN = Cn + ((long)batch << 22);
#pragma unroll
    for (int ci = 0; ci < 2; ++ci)
#pragma unroll
      for (int sj = 0; sj < 4; ++sj) {
        u16x4 o;
#pragma unroll
        for (int r = 0; r < 4; ++r) o[r] = f2b_u(silu_f(acc2[ci][sj][r]));
        int seq = s0 + (sj << 4) + l16;
        *(u16x4*)(dstN + (long)seq * 512 + n0 + wn + (ci << 4) + rq) = o;
      }
  }
}

// ---------- QtV: C2f[b][e][d] += sum_n V'[n,e] Q'[n,d]  (split-K=8, atomics) ----------
__global__ __launch_bounds__(256) void gemm_qtv(
    const unsigned short* __restrict__ A, const unsigned short* __restrict__ B,
    float* __restrict__ Cp) {
  __shared__ __align__(16) unsigned short smem[18432];
  unsigned short(*sA)[72] = (unsigned short(*)[72])smem;
  unsigned short(*sB)[72] = (unsigned short(*)[72])(smem + 9216);

  const int blk = blockIdx.x;
  const int low3 = blk & 7, hi = blk >> 3;
  const int m = ((low3 & 1) << 1) | (hi & 1);
  const int n = (low3 & 2) | ((hi >> 1) & 1);
  const int z = ((hi >> 2) << 1) | (low3 >> 2);  // 0..31
  const int batch = z >> 3, kc = z & 7;          // K-chunk 1024
  const unsigned short* A0 = A + (long)batch * 4194304 + (long)kc * 1024;
  const unsigned short* B0 = B + (long)batch * 4194304 + (long)kc * 1024;
  const int m0 = m << 7, n0 = n << 7;
  const int tid = threadIdx.x;
  const int lane = tid & 63, wave = tid >> 6;
  const int wm = (wave & 1) << 6, wn = (wave >> 1) << 6;
  const int l16 = lane & 15, q8 = (lane >> 4) << 3;

  f32x4 acc[4][4] = {};

  for (int kt = 0; kt < 1024; kt += 64) {
    u16x8 ra[4], rb[4];
#pragma unroll
    for (int i = 0; i < 4; ++i) {
      int c = tid + (i << 8);
      int row = c >> 3, col = (c & 7) << 3;
      ra[i] = *(const u16x8*)(A0 + (long)(m0 + row) * 8192 + kt + col);
      rb[i] = *(const u16x8*)(B0 + (long)(n0 + row) * 8192 + kt + col);
    }
    __syncthreads();
#pragma unroll
    for (int i = 0; i < 4; ++i) {
      int c = tid + (i << 8);
      int row = c >> 3, col = (c & 7) << 3;
      *(u16x8*)&sA[row][col] = ra[i];
      *(u16x8*)&sB[row][col] = rb[i];
    }
    __syncthreads();
#pragma unroll
    for (int kk = 0; kk < 2; ++kk) {
      bf16x8 af[4], bfv[4];
#pragma unroll
      for (int i = 0; i < 4; ++i) {
        af[i] = *(const bf16x8*)&sA[wm + (i << 4) + l16][(kk << 5) + q8];
        bfv[i] = *(const bf16x8*)&sB[wn + (i << 4) + l16][(kk << 5) + q8];
      }
#pragma unroll
      for (int i = 0; i < 4; ++i)
#pragma unroll
        for (int j = 0; j < 4; ++j)
          acc[i][j] = __builtin_amdgcn_mfma_f32_16x16x32_bf16(af[i], bfv[j], acc[i][j], 0, 0, 0);
    }
  }

  const int rq = (lane >> 4) << 2;
#pragma unroll
  for (int i = 0; i < 4; ++i)
#pragma unroll
    for (int j = 0; j < 4; ++j)
#pragma unroll
      for (int r = 0; r < 4; ++r) {
        int gm = m0 + wm + (i << 4) + rq + r;
        int gn = n0 + wn + (j << 4) + l16;
        atomicAdd(Cp + (long)batch * 262144 + (long)gm * 512 + gn, acc[i][j][r]);
      }
}

// ---------- per-(batch,d) column mean of C2f[b][e][d] over e ----------
__global__ __launch_bounds__(64) void colmean(const float* __restrict__ C, float* __restrict__ Cd) {
  const int bd = blockIdx.x;
  const int b = bd >> 9, d = bd & 511;
  const float* p = C + ((long)b << 18) + d;
  float s = 0.f;
  for (int e = threadIdx.x; e < 512; e += 64) s += p[(long)e << 9];
  s += __shfl_xor(s, 1);
  s += __shfl_xor(s, 2);
  s += __shfl_xor(s, 4);
  s += __shfl_xor(s, 8);
  s += __shfl_xor(s, 16);
  s += __shfl_xor(s, 32);
  if (threadIdx.x == 0) Cd[bd] = s * (1.f / 512.f);
}

// ---------- centered fp32 -> bf16 + scalar passthrough ----------
__global__ __launch_bounds__(256) void cvt_center(const float* __restrict__ in,
                                                  const float* __restrict__ Cd,
                                                  unsigned short* __restrict__ out,
                                                  const float* __restrict__ Sh,
                                                  const float* __restrict__ Sc,
                                                  float* __restrict__ outp) {
  int i = (blockIdx.x * 256 + threadIdx.x) * 4;
  f32x4 x = *(const f32x4*)(in + i);
  int b = i >> 18, d = i & 511;
  f32x4 c = *(const f32x4*)(Cd + (b << 9) + d);
  u16x4 o;
#pragma unroll
  for (int j = 0; j < 4; ++j) o[j] = f2b_u(x[j] - c[j]);
  *(u16x4*)(out + i) = o;
  if (blockIdx.x == 0 && threadIdx.x == 0) {
    outp[16777216] = Sh[0];
    outp[16777217] = Sc[0];
  }
}

// ---------- GEMM4 + fused GroupNorm ----------
__global__ __launch_bounds__(256) void gemm4_gn(
    const unsigned short* __restrict__ A, const unsigned short* __restrict__ B,
    const float* __restrict__ gnw, const float* __restrict__ gnb,
    float* __restrict__ out) {
  __shared__ __align__(16) unsigned short smem[18432];
  unsigned short(*sA)[72] = (unsigned short(*)[72])smem;
  unsigned short(*sB)[72] = (unsigned short(*)[72])(smem + 9216);

  const int blk = blockIdx.x;
  const int mt = blk & 255, n = blk >> 8;
  const int batch = mt >> 6;
  const int m0 = (mt & 63) << 7, n0 = n << 7;
  const unsigned short* A0 = A + (long)batch * 4194304;
  const unsigned short* B0 = B + (long)batch * 262144;
  const int tid = threadIdx.x;
  const int lane = tid & 63, wave = tid >> 6;
  const int wm = (wave & 1) << 6, wn = (wave >> 1) << 6;
  const int l16 = lane & 15, q8 = (lane >> 4) << 3;

  f32x4 acc[4][4] = {};

  for (int kt = 0; kt < 512; kt += 64) {
    u16x8 ra[4], rb[4];
#pragma unroll
    for (int i = 0; i < 4; ++i) {
      int c = tid + (i << 8);
      int row = c >> 3, col = (c & 7) << 3;
      ra[i] = *(const u16x8*)(A0 + (long)(m0 + row) * 512 + kt + col);
      rb[i] = *(const u16x8*)(B0 + (long)(n0 + row) * 512 + kt + col);
    }
    __syncthreads();
#pragma unroll
    for (int i = 0; i < 4; ++i) {
      int c = tid + (i << 8);
      int row = c >> 3, col = (c & 7) << 3;
      *(u16x8*)&sA[row][col] = ra[i];
      *(u16x8*)&sB[row][col] = rb[i];
    }
    __syncthreads();
#pragma unroll
    for (int kk = 0; kk < 2; ++kk) {
      bf16x8 af[4], bfv[4];
#pragma unroll
      for (int i = 0; i < 4; ++i) {
        af[i] = *(const bf16x8*)&sA[wm + (i << 4) + l16][(kk << 5) + q8];
        bfv[i] = *(const bf16x8*)&sB[wn + (i << 4) + l16][(kk << 5) + q8];
      }
#pragma unroll
      for (int i = 0; i < 4; ++i)
#pragma unroll
        for (int j = 0; j < 4; ++j)
          acc[i][j] = __builtin_amdgcn_mfma_f32_16x16x32_bf16(af[i], bfv[j], acc[i][j], 0, 0, 0);
    }
  }

  const int rq = (lane >> 4) << 2;
  float wv[4], bb[4];
#pragma unroll
  for (int j = 0; j < 4; ++j) {
    int gn = n0 + wn + (j << 4) + l16;
    wv[j] = gnw[gn];
    bb[j] = gnb[gn];
  }
  float* obase = out + (long)batch * 4194304;
#pragma unroll
  for (int i = 0; i < 4; ++i) {
    float mean[4], inv[4];
#pragma unroll
    for (int r = 0; r < 4; ++r) {
      float s = acc[i][0][r] + acc[i][1][r] + acc[i][2][r] + acc[i][3][r];
      s += __shfl_xor(s, 1);
      s += __shfl_xor(s, 2);
      s += __shfl_xor(s, 4);
      s += __shfl_xor(s, 8);
      mean[r] = s * (1.f / 64.f);
      float sq = 0.f;
#pragma unroll
      for (int j = 0; j < 4; ++j) {
        float d = acc[i][j][r] - mean[r];
        sq += d * d;
      }
      sq += __shfl_xor(sq, 1);
      sq += __shfl_xor(sq, 2);
      sq += __shfl_xor(sq, 4);
      sq += __shfl_xor(sq, 8);
      inv[r] = rsqrtf(sq * (1.f / 64.f) + 1e-6f);
    }
#pragma unroll
    for (int j = 0; j < 4; ++j) {
      int gn = n0 + wn + (j << 4) + l16;
#pragma unroll
      for (int r = 0; r < 4; ++r) {
        int gm = m0 + wm + (i << 4) + rq + r;
        obase[(long)gm * 512 + gn] = (acc[i][j][r] - mean[r]) * inv[r] * wv[j] + bb[j];
      }
    }
  }
}

// ---------- launch ----------
extern "C" void kernel_launch(void* const* d_in, const int* in_sizes, int n_in,
                              void* d_out, int out_size, void* d_ws, size_t ws_size,
                              hipStream_t stream) {
  const float* Xq = (const float*)d_in[0];
  const float* Xkv = (const float*)d_in[1];
  const float* Sh = (const float*)d_in[2];
  const float* Sc = (const float*)d_in[3];
  const float* Wq = (const float*)d_in[4];
  const float* bq = (const float*)d_in[5];
  // d_in[6]=Wk, d_in[7]=bk : dead code in reference
  const float* Wv = (const float*)d_in[8];
  const float* bv = (const float*)d_in[9];
  const float* gnw = (const float*)d_in[10];
  const float* gnb = (const float*)d_in[11];

  char* ws = (char*)d_ws;
  // layout (bytes), peak = 106,962,944 (proven available):
  unsigned short* QT = (unsigned short*)(ws);                // [4][512][8192] bf16
  unsigned short* VT = (unsigned short*)(ws + 33554432L);
  unsigned short* Kn = (unsigned short*)(ws + 67108864L);    // [4][8192][512] bf16
  float* C2f = (float*)(ws + 100663296L);                    // [4][512][512] f32 = 4 MB
  unsigned short* C2c = (unsigned short*)(ws + 104857600L);  // 2 MB
  float* Cd = (float*)(ws + 106954752L);                     // 8 KB
  // proj-phase overlays in the C2f region (dead until memset):
  unsigned short* Wqb = (unsigned short*)(ws + 100663296L);             // 0.5 MB
  unsigned short* Wvb = (unsigned short*)(ws + 100663296L + 524288L);   // 0.5 MB
  float* TBL = (float*)(ws + 100663296L + 1048576L);                    // 2 MB
  float* outp = (float*)d_out;

  if (ws_size < 106962944UL) return;

  // 0: weights fp32 -> bf16; rope table
  cvt_w<<<256, 256, 0, stream>>>(Wq, Wqb);
  cvt_w<<<256, 256, 0, stream>>>(Wv, Wvb);
  gen_tbl<<<1024, 256, 0, stream>>>(TBL);

  // 1+2: projections — proven 2-barrier structure, register-direct epilogues
  proj4<0><<<1024, 512, 0, stream>>>(Xq, Wqb, QT, bq, nullptr, TBL);
  proj4<1><<<1024, 512, 0, stream>>>(Xkv, Wvb, VT, bv, Kn, TBL);

  // 3: QtV^T accumulation (split-K=8, fp32 atomics)
  (void)hipMemsetAsync(C2f, 0, 4194304, stream);
  gemm_qtv<<<512, 256, 0, stream>>>(VT, QT, C2f);

  // 3b: center per (b,d), round to bf16; scalar passthrough
  colmean<<<2048, 64, 0, stream>>>(C2f, Cd);
  cvt_center<<<1024, 256, 0, stream>>>(C2f, Cd, C2c, Sh, Sc, outp);

  // 4: out = GroupNorm( K' @ (QtV - Cd) ) fused
  gemm4_gn<<<1024, 256, 0, stream>>>(Kn, C2c, gnw, gnb, outp);
}

// Round 3
// 360.766 us; speedup vs baseline: 1.1210x; 1.0629x over previous
//
#include <hip/hip_runtime.h>

// ---------- types ----------
typedef __bf16 bf16x8 __attribute__((ext_vector_type(8)));
typedef float f32x4 __attribute__((ext_vector_type(4)));
typedef unsigned short u16x8 __attribute__((ext_vector_type(8)));
typedef unsigned short u16x4 __attribute__((ext_vector_type(4)));

__device__ __forceinline__ unsigned short f2b_u(float f) {
  unsigned int u;
  __builtin_memcpy(&u, &f, 4);
  unsigned int r = 0x7FFFu + ((u >> 16) & 1u);  // round-to-nearest-even
  return (unsigned short)((u + r) >> 16);
}
__device__ __forceinline__ float silu_f(float x) { return x / (1.f + expf(-x)); }

// ---------- fp32 -> bf16 (weights) ----------
__global__ __launch_bounds__(256) void cvt_w(const float* __restrict__ in,
                                             unsigned short* __restrict__ out) {
  int i = (blockIdx.x * 256 + threadIdx.x) * 4;  // grid 256 -> 262144 f32
  f32x4 x = *(const f32x4*)(in + i);
  u16x4 o;
#pragma unroll
  for (int j = 0; j < 4; ++j) o[j] = f2b_u(x[j]);
  *(u16x4*)(out + i) = o;
}

// ---------- rope sin/cos table: TBL[pos][ip] = (sin, cos), pos<8192, ip<32 ----------
__global__ __launch_bounds__(256) void gen_tbl(float* __restrict__ T) {
  int idx = blockIdx.x * 256 + threadIdx.x;  // grid 1024 -> 262144
  int pos = idx >> 5, ip = idx & 31;
  float f = (float)pos * powf(10000.f, -(float)ip * (1.f / 32.f));
  float sn, cs;
  sincosf(f, &sn, &cs);
  T[idx * 2] = sn;
  T[idx * 2 + 1] = cs;
}

// ---------- projection v5: Y = X @ W^T + b ----------
// tile 64m x 256n, block 512 (8 waves, each 64m x 32n), grid 1024 (bid&1 = n-half).
// BK=64: 8 iterations, 2 barriers each (proven-safe gemm_qtv structure), register
// prefetch distance 1 — per-iteration window is 16(32) MFMA + 12 ds_read_b128.
// Register-direct epilogues (no epilogue LDS, no epilogue barriers):
// MODE 0: QT = T(silu(rope(Y)))          via acc  (r<->seq, direct u16x4 stores)
// MODE 1: VT = T(silu(Y))                via acc  (r<->seq)
//         Kn = silu(rope(Y)) natural     via acc2 = swapped-operand mfma (r<->ch,
//              in-lane rope pairs, direct u16x4 stores) — same LDS fragments.
template <int MODE>
__global__ __launch_bounds__(512, 4) void proj5(
    const float* __restrict__ A, const unsigned short* __restrict__ B,
    unsigned short* __restrict__ Ct, const float* __restrict__ bias,
    unsigned short* __restrict__ Cn, const float* __restrict__ TBL) {
  __shared__ __align__(16) unsigned short sA[64][72];   // 9,216 B  (64m x 64k bf16)
  __shared__ __align__(16) unsigned short sB[256][72];  // 36,864 B (256n x 64k bf16)

  const int bid = blockIdx.x;
  const int n0 = (bid & 1) << 8;          // 0 or 256
  const long m0 = (long)(bid >> 1) << 6;  // 64-row m-tiles
  const int tid = threadIdx.x;
  const int lane = tid & 63, w = tid >> 6;
  const int wn = w << 5;  // wave n-offset: 0..224
  const int l16 = lane & 15, q8 = (lane >> 4) << 3, rq = (lane >> 4) << 2;
  const int ar = tid >> 3, ac = (tid & 7) << 2;  // A stage: 64 rows x 64k f32, 2 loads
  const int br = tid >> 1, bc = (tid & 1) << 5;  // B stage: 256 rows x 64k bf16, 64 B/thread

  const float* Ap = A + (m0 + ar) * 512 + ac;
  const unsigned short* Bp = B + (long)(n0 + br) * 512 + bc;

  f32x4 acc[4][2] = {};
  f32x4 acc2[2][4] = {};  // MODE 1 only (DCE'd in MODE 0)

  // prologue: load k-tile 0 into registers
  f32x4 a0 = *(const f32x4*)Ap;
  f32x4 a1 = *(const f32x4*)(Ap + 32);
  u16x8 b0 = *(const u16x8*)Bp;
  u16x8 b1 = *(const u16x8*)(Bp + 8);
  u16x8 b2 = *(const u16x8*)(Bp + 16);
  u16x8 b3 = *(const u16x8*)(Bp + 24);

  for (int kt = 0; kt < 512; kt += 64) {
    __syncthreads();  // previous iteration's LDS readers are done
    {
      u16x4 lo, hi;
#pragma unroll
      for (int j = 0; j < 4; ++j) {
        lo[j] = f2b_u(a0[j]);
        hi[j] = f2b_u(a1[j]);
      }
      *(u16x4*)&sA[ar][ac] = lo;
      *(u16x4*)&sA[ar][ac + 32] = hi;
      *(u16x8*)&sB[br][bc] = b0;
      *(u16x8*)&sB[br][bc + 8] = b1;
      *(u16x8*)&sB[br][bc + 16] = b2;
      *(u16x8*)&sB[br][bc + 24] = b3;
    }
    __syncthreads();  // tile visible to all waves
    if (kt < 448) {   // prefetch next k-tile into registers, hidden under MFMAs
      a0 = *(const f32x4*)(Ap + kt + 64);
      a1 = *(const f32x4*)(Ap + kt + 96);
      b0 = *(const u16x8*)(Bp + kt + 64);
      b1 = *(const u16x8*)(Bp + kt + 72);
      b2 = *(const u16x8*)(Bp + kt + 80);
      b3 = *(const u16x8*)(Bp + kt + 88);
    }
#pragma unroll
    for (int kk = 0; kk < 2; ++kk) {
      bf16x8 af[4], bf[2];
#pragma unroll
      for (int i = 0; i < 4; ++i)
        af[i] = *(const bf16x8*)&sA[(i << 4) + l16][(kk << 5) + q8];
#pragma unroll
      for (int j = 0; j < 2; ++j)
        bf[j] = *(const bf16x8*)&sB[wn + (j << 4) + l16][(kk << 5) + q8];
#pragma unroll
      for (int i = 0; i < 4; ++i)
#pragma unroll
        for (int j = 0; j < 2; ++j)
          acc[i][j] = __builtin_amdgcn_mfma_f32_16x16x32_bf16(af[i], bf[j], acc[i][j], 0, 0, 0);
      if (MODE == 1) {
#pragma unroll
        for (int ci = 0; ci < 2; ++ci)
#pragma unroll
          for (int sj = 0; sj < 4; ++sj)
            acc2[ci][sj] =
                __builtin_amdgcn_mfma_f32_16x16x32_bf16(bf[ci], af[sj], acc2[ci][sj], 0, 0, 0);
      }
    }
  }

  const int batch = (int)(m0 >> 13);
  const int s0 = ((int)m0) & 8191;  // rope position base

  // bias for acc (col = ch = l16-indexed)
#pragma unroll
  for (int j = 0; j < 2; ++j) {
    float bv = bias[n0 + wn + (j << 4) + l16];
#pragma unroll
    for (int i = 0; i < 4; ++i)
#pragma unroll
      for (int r = 0; r < 4; ++r) acc[i][j][r] += bv;
  }

  if (MODE == 0) {
    // rope on acc (ch pairs live in adjacent lanes -> shfl_xor 1)
    if (n0 + wn < 64) {
#pragma unroll
      for (int j = 0; j < 2; ++j) {
        int ip = ((wn + (j << 4)) >> 1) + (l16 >> 1);
        float sgn = (l16 & 1) ? 1.f : -1.f;
#pragma unroll
        for (int i = 0; i < 4; ++i)
#pragma unroll
          for (int r = 0; r < 4; ++r) {
            int pos = s0 + (i << 4) + rq + r;
            const float* t = TBL + ((long)pos << 6) + (ip << 1);
            float sn = t[0], cs = t[1];
            float v = acc[i][j][r];
            float p = __shfl_xor(v, 1);
            acc[i][j][r] = v * cs + sgn * sn * p;
          }
      }
    }
  }

  // transposed store (QT in MODE 0, VT in MODE 1): r-run = 4 consecutive seq
  {
    unsigned short* dstT = Ct + ((long)batch << 22);
#pragma unroll
    for (int i = 0; i < 4; ++i)
#pragma unroll
      for (int j = 0; j < 2; ++j) {
        u16x4 o;
#pragma unroll
        for (int r = 0; r < 4; ++r) o[r] = f2b_u(silu_f(acc[i][j][r]));
        *(u16x4*)(dstT + (long)(n0 + wn + (j << 4) + l16) * 8192 + s0 + (i << 4) + rq) = o;
      }
  }

  if (MODE == 1) {
    // acc2: row = ch (rq+r), col = seq (l16)
#pragma unroll
    for (int ci = 0; ci < 2; ++ci) {
      float bv2[4];
#pragma unroll
      for (int r = 0; r < 4; ++r) bv2[r] = bias[n0 + wn + (ci << 4) + rq + r];
#pragma unroll
      for (int sj = 0; sj < 4; ++sj)
#pragma unroll
        for (int r = 0; r < 4; ++r) acc2[ci][sj][r] += bv2[r];
    }
    if (n0 + wn < 64) {  // rope: ch pairs are (r, r+1) within the lane — no shuffle
#pragma unroll
      for (int ci = 0; ci < 2; ++ci)
#pragma unroll
        for (int sj = 0; sj < 4; ++sj) {
          int pos = s0 + (sj << 4) + l16;
          const float* tb = TBL + ((long)pos << 6);
#pragma unroll
          for (int rp = 0; rp < 4; rp += 2) {
            int ip = (wn + (ci << 4) + rq + rp) >> 1;
            float sn = tb[ip << 1], cs = tb[(ip << 1) + 1];
            float v0 = acc2[ci][sj][rp], v1 = acc2[ci][sj][rp + 1];
            acc2[ci][sj][rp] = v0 * cs - sn * v1;
            acc2[ci][sj][rp + 1] = v1 * cs + sn * v0;
          }
        }
    }
    unsigned short* dstN = Cn + ((long)batch << 22);
#pragma unroll
    for (int ci = 0; ci < 2; ++ci)
#pragma unroll
      for (int sj = 0; sj < 4; ++sj) {
        u16x4 o;
#pragma unroll
        for (int r = 0; r < 4; ++r) o[r] = f2b_u(silu_f(acc2[ci][sj][r]));
        int seq = s0 + (sj << 4) + l16;
        *(u16x4*)(dstN + (long)seq * 512 + n0 + wn + (ci << 4) + rq) = o;
      }
  }
}

// ---------- QtV: C2f[b][e][d] += sum_n V'[n,e] Q'[n,d]  (split-K=8, atomics) ----------
__global__ __launch_bounds__(256) void gemm_qtv(
    const unsigned short* __restrict__ A, const unsigned short* __restrict__ B,
    float* __restrict__ Cp) {
  __shared__ __align__(16) unsigned short smem[18432];
  unsigned short(*sA)[72] = (unsigned short(*)[72])smem;
  unsigned short(*sB)[72] = (unsigned short(*)[72])(smem + 9216);

  const int blk = blockIdx.x;
  const int low3 = blk & 7, hi = blk >> 3;
  const int m = ((low3 & 1) << 1) | (hi & 1);
  const int n = (low3 & 2) | ((hi >> 1) & 1);
  const int z = ((hi >> 2) << 1) | (low3 >> 2);  // 0..31
  const int batch = z >> 3, kc = z & 7;          // K-chunk 1024
  const unsigned short* A0 = A + (long)batch * 4194304 + (long)kc * 1024;
  const unsigned short* B0 = B + (long)batch * 4194304 + (long)kc * 1024;
  const int m0 = m << 7, n0 = n << 7;
  const int tid = threadIdx.x;
  const int lane = tid & 63, wave = tid >> 6;
  const int wm = (wave & 1) << 6, wn = (wave >> 1) << 6;
  const int l16 = lane & 15, q8 = (lane >> 4) << 3;

  f32x4 acc[4][4] = {};

  for (int kt = 0; kt < 1024; kt += 64) {
    u16x8 ra[4], rb[4];
#pragma unroll
    for (int i = 0; i < 4; ++i) {
      int c = tid + (i << 8);
      int row = c >> 3, col = (c & 7) << 3;
      ra[i] = *(const u16x8*)(A0 + (long)(m0 + row) * 8192 + kt + col);
      rb[i] = *(const u16x8*)(B0 + (long)(n0 + row) * 8192 + kt + col);
    }
    __syncthreads();
#pragma unroll
    for (int i = 0; i < 4; ++i) {
      int c = tid + (i << 8);
      int row = c >> 3, col = (c & 7) << 3;
      *(u16x8*)&sA[row][col] = ra[i];
      *(u16x8*)&sB[row][col] = rb[i];
    }
    __syncthreads();
#pragma unroll
    for (int kk = 0; kk < 2; ++kk) {
      bf16x8 af[4], bfv[4];
#pragma unroll
      for (int i = 0; i < 4; ++i) {
        af[i] = *(const bf16x8*)&sA[wm + (i << 4) + l16][(kk << 5) + q8];
        bfv[i] = *(const bf16x8*)&sB[wn + (i << 4) + l16][(kk << 5) + q8];
      }
#pragma unroll
      for (int i = 0; i < 4; ++i)
#pragma unroll
        for (int j = 0; j < 4; ++j)
          acc[i][j] = __builtin_amdgcn_mfma_f32_16x16x32_bf16(af[i], bfv[j], acc[i][j], 0, 0, 0);
    }
  }

  const int rq = (lane >> 4) << 2;
#pragma unroll
  for (int i = 0; i < 4; ++i)
#pragma unroll
    for (int j = 0; j < 4; ++j)
#pragma unroll
      for (int r = 0; r < 4; ++r) {
        int gm = m0 + wm + (i << 4) + rq + r;
        int gn = n0 + wn + (j << 4) + l16;
        atomicAdd(Cp + (long)batch * 262144 + (long)gm * 512 + gn, acc[i][j][r]);
      }
}

// ---------- per-(batch,d) column mean of C2f[b][e][d] over e ----------
__global__ __launch_bounds__(64) void colmean(const float* __restrict__ C, float* __restrict__ Cd) {
  const int bd = blockIdx.x;
  const int b = bd >> 9, d = bd & 511;
  const float* p = C + ((long)b << 18) + d;
  float s = 0.f;
  for (int e = threadIdx.x; e < 512; e += 64) s += p[(long)e << 9];
  s += __shfl_xor(s, 1);
  s += __shfl_xor(s, 2);
  s += __shfl_xor(s, 4);
  s += __shfl_xor(s, 8);
  s += __shfl_xor(s, 16);
  s += __shfl_xor(s, 32);
  if (threadIdx.x == 0) Cd[bd] = s * (1.f / 512.f);
}

// ---------- centered fp32 -> bf16 + scalar passthrough ----------
__global__ __launch_bounds__(256) void cvt_center(const float* __restrict__ in,
                                                  const float* __restrict__ Cd,
                                                  unsigned short* __restrict__ out,
                                                  const float* __restrict__ Sh,
                                                  const float* __restrict__ Sc,
                                                  float* __restrict__ outp) {
  int i = (blockIdx.x * 256 + threadIdx.x) * 4;
  f32x4 x = *(const f32x4*)(in + i);
  int b = i >> 18, d = i & 511;
  f32x4 c = *(const f32x4*)(Cd + (b << 9) + d);
  u16x4 o;
#pragma unroll
  for (int j = 0; j < 4; ++j) o[j] = f2b_u(x[j] - c[j]);
  *(u16x4*)(out + i) = o;
  if (blockIdx.x == 0 && threadIdx.x == 0) {
    outp[16777216] = Sh[0];
    outp[16777217] = Sc[0];
  }
}

// ---------- GEMM4 + fused GroupNorm ----------
__global__ __launch_bounds__(256) void gemm4_gn(
    const unsigned short* __restrict__ A, const unsigned short* __restrict__ B,
    const float* __restrict__ gnw, const float* __restrict__ gnb,
    float* __restrict__ out) {
  __shared__ __align__(16) unsigned short smem[18432];
  unsigned short(*sA)[72] = (unsigned short(*)[72])smem;
  unsigned short(*sB)[72] = (unsigned short(*)[72])(smem + 9216);

  const int blk = blockIdx.x;
  const int mt = blk & 255, n = blk >> 8;
  const int batch = mt >> 6;
  const int m0 = (mt & 63) << 7, n0 = n << 7;
  const unsigned short* A0 = A + (long)batch * 4194304;
  const unsigned short* B0 = B + (long)batch * 262144;
  const int tid = threadIdx.x;
  const int lane = tid & 63, wave = tid >> 6;
  const int wm = (wave & 1) << 6, wn = (wave >> 1) << 6;
  const int l16 = lane & 15, q8 = (lane >> 4) << 3;

  f32x4 acc[4][4] = {};

  for (int kt = 0; kt < 512; kt += 64) {
    u16x8 ra[4], rb[4];
#pragma unroll
    for (int i = 0; i < 4; ++i) {
      int c = tid + (i << 8);
      int row = c >> 3, col = (c & 7) << 3;
      ra[i] = *(const u16x8*)(A0 + (long)(m0 + row) * 512 + kt + col);
      rb[i] = *(const u16x8*)(B0 + (long)(n0 + row) * 512 + kt + col);
    }
    __syncthreads();
#pragma unroll
    for (int i = 0; i < 4; ++i) {
      int c = tid + (i << 8);
      int row = c >> 3, col = (c & 7) << 3;
      *(u16x8*)&sA[row][col] = ra[i];
      *(u16x8*)&sB[row][col] = rb[i];
    }
    __syncthreads();
#pragma unroll
    for (int kk = 0; kk < 2; ++kk) {
      bf16x8 af[4], bfv[4];
#pragma unroll
      for (int i = 0; i < 4; ++i) {
        af[i] = *(const bf16x8*)&sA[wm + (i << 4) + l16][(kk << 5) + q8];
        bfv[i] = *(const bf16x8*)&sB[wn + (i << 4) + l16][(kk << 5) + q8];
      }
#pragma unroll
      for (int i = 0; i < 4; ++i)
#pragma unroll
        for (int j = 0; j < 4; ++j)
          acc[i][j] = __builtin_amdgcn_mfma_f32_16x16x32_bf16(af[i], bfv[j], acc[i][j], 0, 0, 0);
    }
  }

  const int rq = (lane >> 4) << 2;
  float wv[4], bb[4];
#pragma unroll
  for (int j = 0; j < 4; ++j) {
    int gn = n0 + wn + (j << 4) + l16;
    wv[j] = gnw[gn];
    bb[j] = gnb[gn];
  }
  float* obase = out + (long)batch * 4194304;
#pragma unroll
  for (int i = 0; i < 4; ++i) {
    float mean[4], inv[4];
#pragma unroll
    for (int r = 0; r < 4; ++r) {
      float s = acc[i][0][r] + acc[i][1][r] + acc[i][2][r] + acc[i][3][r];
      s += __shfl_xor(s, 1);
      s += __shfl_xor(s, 2);
      s += __shfl_xor(s, 4);
      s += __shfl_xor(s, 8);
      mean[r] = s * (1.f / 64.f);
      float sq = 0.f;
#pragma unroll
      for (int j = 0; j < 4; ++j) {
        float d = acc[i][j][r] - mean[r];
        sq += d * d;
      }
      sq += __shfl_xor(sq, 1);
      sq += __shfl_xor(sq, 2);
      sq += __shfl_xor(sq, 4);
      sq += __shfl_xor(sq, 8);
      inv[r] = rsqrtf(sq * (1.f / 64.f) + 1e-6f);
    }
#pragma unroll
    for (int j = 0; j < 4; ++j) {
      int gn = n0 + wn + (j << 4) + l16;
#pragma unroll
      for (int r = 0; r < 4; ++r) {
        int gm = m0 + wm + (i << 4) + rq + r;
        obase[(long)gm * 512 + gn] = (acc[i][j][r] - mean[r]) * inv[r] * wv[j] + bb[j];
      }
    }
  }
}

// ---------- launch ----------
extern "C" void kernel_launch(void* const* d_in, const int* in_sizes, int n_in,
                              void* d_out, int out_size, void* d_ws, size_t ws_size,
                              hipStream_t stream) {
  const float* Xq = (const float*)d_in[0];
  const float* Xkv = (const float*)d_in[1];
  const float* Sh = (const float*)d_in[2];
  const float* Sc = (const float*)d_in[3];
  const float* Wq = (const float*)d_in[4];
  const float* bq = (const float*)d_in[5];
  // d_in[6]=Wk, d_in[7]=bk : dead code in reference
  const float* Wv = (const float*)d_in[8];
  const float* bv = (const float*)d_in[9];
  const float* gnw = (const float*)d_in[10];
  const float* gnb = (const float*)d_in[11];

  char* ws = (char*)d_ws;
  // layout (bytes), peak = 106,962,944 (proven available):
  unsigned short* QT = (unsigned short*)(ws);                // [4][512][8192] bf16
  unsigned short* VT = (unsigned short*)(ws + 33554432L);
  unsigned short* Kn = (unsigned short*)(ws + 67108864L);    // [4][8192][512] bf16
  float* C2f = (float*)(ws + 100663296L);                    // [4][512][512] f32 = 4 MB
  unsigned short* C2c = (unsigned short*)(ws + 104857600L);  // 2 MB
  float* Cd = (float*)(ws + 106954752L);                     // 8 KB
  // proj-phase overlays in the C2f region (dead until memset):
  unsigned short* Wqb = (unsigned short*)(ws + 100663296L);             // 0.5 MB
  unsigned short* Wvb = (unsigned short*)(ws + 100663296L + 524288L);   // 0.5 MB
  float* TBL = (float*)(ws + 100663296L + 1048576L);                    // 2 MB
  float* outp = (float*)d_out;

  if (ws_size < 106962944UL) return;

  // 0: weights fp32 -> bf16; rope table
  cvt_w<<<256, 256, 0, stream>>>(Wq, Wqb);
  cvt_w<<<256, 256, 0, stream>>>(Wv, Wvb);
  gen_tbl<<<1024, 256, 0, stream>>>(TBL);

  // 1+2: projections — BK=64, 2-barrier structure, register-direct epilogues
  proj5<0><<<1024, 512, 0, stream>>>(Xq, Wqb, QT, bq, nullptr, TBL);
  proj5<1><<<1024, 512, 0, stream>>>(Xkv, Wvb, VT, bv, Kn, TBL);

  // 3: QtV^T accumulation (split-K=8, fp32 atomics)
  (void)hipMemsetAsync(C2f, 0, 4194304, stream);
  gemm_qtv<<<512, 256, 0, stream>>>(VT, QT, C2f);

  // 3b: center per (b,d), round to bf16; scalar passthrough
  colmean<<<2048, 64, 0, stream>>>(C2f, Cd);
  cvt_center<<<1024, 256, 0, stream>>>(C2f, Cd, C2c, Sh, Sc, outp);

  // 4: out = GroupNorm( K' @ (QtV - Cd) ) fused
  gemm4_gn<<<1024, 256, 0, stream>>>(Kn, C2c, gnw, gnb, outp);
}

// Round 5
// 346.137 us; speedup vs baseline: 1.1684x; 1.0423x over previous
//
#include <hip/hip_runtime.h>

// ---------- types ----------
typedef __bf16 bf16x8 __attribute__((ext_vector_type(8)));
typedef float f32x4 __attribute__((ext_vector_type(4)));
typedef unsigned short u16x8 __attribute__((ext_vector_type(8)));
typedef unsigned short u16x4 __attribute__((ext_vector_type(4)));

__device__ __forceinline__ unsigned short f2b_u(float f) {
  unsigned int u;
  __builtin_memcpy(&u, &f, 4);
  unsigned int r = 0x7FFFu + ((u >> 16) & 1u);  // round-to-nearest-even
  return (unsigned short)((u + r) >> 16);
}
__device__ __forceinline__ float silu_f(float x) { return x / (1.f + expf(-x)); }

// ---------- setup: weights fp32->bf16 (2x) + rope table, one launch ----------
// grid 1536: [0,256) Wq, [256,512) Wv, [512,1536) TBL
__global__ __launch_bounds__(256) void setup_k(const float* __restrict__ Wq,
                                               const float* __restrict__ Wv,
                                               unsigned short* __restrict__ Wqb,
                                               unsigned short* __restrict__ Wvb,
                                               float* __restrict__ T) {
  int b = blockIdx.x;
  if (b < 512) {
    const float* in = (b < 256) ? Wq : Wv;
    unsigned short* out = (b < 256) ? Wqb : Wvb;
    int i = ((b & 255) * 256 + threadIdx.x) * 4;
    f32x4 x = *(const f32x4*)(in + i);
    u16x4 o;
#pragma unroll
    for (int j = 0; j < 4; ++j) o[j] = f2b_u(x[j]);
    *(u16x4*)(out + i) = o;
  } else {
    int idx = (b - 512) * 256 + threadIdx.x;  // 262144
    int pos = idx >> 5, ip = idx & 31;
    float f = (float)pos * powf(10000.f, -(float)ip * (1.f / 32.f));
    float sn, cs;
    sincosf(f, &sn, &cs);
    T[idx * 2] = sn;
    T[idx * 2 + 1] = cs;
  }
}

// ---------- projection v6: BOTH projections in one launch ----------
// blockIdx.x 0..2047: mode = bid&1 (0: Q-proj, 1: V/K-proj), t = bid>>1.
// tile 64m x 256n, block 512 (8 waves, each 64m x 32n), n0 = (t&1)*256, m0 = (t>>1)*64.
// MODE0 and MODE1 blocks co-resident on each CU -> heterogeneous latency hiding.
// BK=64, proven 2-barrier structure, register prefetch distance 1.
// Register-direct epilogues:
// mode 0: QT = T(silu(rope(Y)))          via acc  (r<->seq, direct u16x4 stores)
// mode 1: VT = T(silu(Y))                via acc  (r<->seq)
//         Kn = silu(rope(Y)) natural     via acc2 = swapped-operand mfma (r<->ch,
//              in-lane rope pairs, direct u16x4 stores) — same LDS fragments.
__global__ __launch_bounds__(512, 4) void proj6(
    const float* __restrict__ Xq, const float* __restrict__ Xkv,
    const unsigned short* __restrict__ Wqb, const unsigned short* __restrict__ Wvb,
    const float* __restrict__ bq, const float* __restrict__ bv,
    unsigned short* __restrict__ QT, unsigned short* __restrict__ VT,
    unsigned short* __restrict__ Kn, const float* __restrict__ TBL) {
  __shared__ __align__(16) unsigned short sA[64][72];   // 9,216 B  (64m x 64k bf16)
  __shared__ __align__(16) unsigned short sB[256][72];  // 36,864 B (256n x 64k bf16)

  const int mode = blockIdx.x & 1;
  const int t = blockIdx.x >> 1;
  const float* A = mode ? Xkv : Xq;
  const unsigned short* B = mode ? Wvb : Wqb;
  const float* bias = mode ? bv : bq;
  unsigned short* Ct = mode ? VT : QT;

  const int n0 = (t & 1) << 8;          // 0 or 256
  const long m0 = (long)(t >> 1) << 6;  // 64-row m-tiles
  const int tid = threadIdx.x;
  const int lane = tid & 63, w = tid >> 6;
  const int wn = w << 5;  // wave n-offset: 0..224
  const int l16 = lane & 15, q8 = (lane >> 4) << 3, rq = (lane >> 4) << 2;
  const int ar = tid >> 3, ac = (tid & 7) << 2;  // A stage: 64 rows x 64k f32
  const int br = tid >> 1, bc = (tid & 1) << 5;  // B stage: 256 rows x 64k bf16

  const float* Ap = A + (m0 + ar) * 512 + ac;
  const unsigned short* Bp = B + (long)(n0 + br) * 512 + bc;

  f32x4 acc[4][2] = {};
  f32x4 acc2[2][4] = {};  // used when mode==1

  // prologue: load k-tile 0 into registers
  f32x4 a0 = *(const f32x4*)Ap;
  f32x4 a1 = *(const f32x4*)(Ap + 32);
  u16x8 b0 = *(const u16x8*)Bp;
  u16x8 b1 = *(const u16x8*)(Bp + 8);
  u16x8 b2 = *(const u16x8*)(Bp + 16);
  u16x8 b3 = *(const u16x8*)(Bp + 24);

  for (int kt = 0; kt < 512; kt += 64) {
    __syncthreads();  // previous iteration's LDS readers are done
    {
      u16x4 lo, hi;
#pragma unroll
      for (int j = 0; j < 4; ++j) {
        lo[j] = f2b_u(a0[j]);
        hi[j] = f2b_u(a1[j]);
      }
      *(u16x4*)&sA[ar][ac] = lo;
      *(u16x4*)&sA[ar][ac + 32] = hi;
      *(u16x8*)&sB[br][bc] = b0;
      *(u16x8*)&sB[br][bc + 8] = b1;
      *(u16x8*)&sB[br][bc + 16] = b2;
      *(u16x8*)&sB[br][bc + 24] = b3;
    }
    __syncthreads();  // tile visible to all waves
    if (kt < 448) {   // prefetch next k-tile into registers, hidden under MFMAs
      a0 = *(const f32x4*)(Ap + kt + 64);
      a1 = *(const f32x4*)(Ap + kt + 96);
      b0 = *(const u16x8*)(Bp + kt + 64);
      b1 = *(const u16x8*)(Bp + kt + 72);
      b2 = *(const u16x8*)(Bp + kt + 80);
      b3 = *(const u16x8*)(Bp + kt + 88);
    }
#pragma unroll
    for (int kk = 0; kk < 2; ++kk) {
      bf16x8 af[4], bf[2];
#pragma unroll
      for (int i = 0; i < 4; ++i) af[i] = *(const bf16x8*)&sA[(i << 4) + l16][(kk << 5) + q8];
#pragma unroll
      for (int j = 0; j < 2; ++j) bf[j] = *(const bf16x8*)&sB[wn + (j << 4) + l16][(kk << 5) + q8];
#pragma unroll
      for (int i = 0; i < 4; ++i)
#pragma unroll
        for (int j = 0; j < 2; ++j)
          acc[i][j] = __builtin_amdgcn_mfma_f32_16x16x32_bf16(af[i], bf[j], acc[i][j], 0, 0, 0);
      if (mode == 1) {
#pragma unroll
        for (int ci = 0; ci < 2; ++ci)
#pragma unroll
          for (int sj = 0; sj < 4; ++sj)
            acc2[ci][sj] =
                __builtin_amdgcn_mfma_f32_16x16x32_bf16(bf[ci], af[sj], acc2[ci][sj], 0, 0, 0);
      }
    }
  }

  const int batch = (int)(m0 >> 13);
  const int s0 = ((int)m0) & 8191;  // rope position base

  // bias for acc (col = ch = l16-indexed)
#pragma unroll
  for (int j = 0; j < 2; ++j) {
    float bv_ = bias[n0 + wn + (j << 4) + l16];
#pragma unroll
    for (int i = 0; i < 4; ++i)
#pragma unroll
      for (int r = 0; r < 4; ++r) acc[i][j][r] += bv_;
  }

  if (mode == 0) {
    // rope on acc (ch pairs live in adjacent lanes -> shfl_xor 1)
    if (n0 + wn < 64) {
#pragma unroll
      for (int j = 0; j < 2; ++j) {
        int ip = ((wn + (j << 4)) >> 1) + (l16 >> 1);
        float sgn = (l16 & 1) ? 1.f : -1.f;
#pragma unroll
        for (int i = 0; i < 4; ++i)
#pragma unroll
          for (int r = 0; r < 4; ++r) {
            int pos = s0 + (i << 4) + rq + r;
            const float* tb = TBL + ((long)pos << 6) + (ip << 1);
            float sn = tb[0], cs = tb[1];
            float v = acc[i][j][r];
            float p = __shfl_xor(v, 1);
            acc[i][j][r] = v * cs + sgn * sn * p;
          }
      }
    }
  }

  // transposed store (QT mode 0, VT mode 1): r-run = 4 consecutive seq
  {
    unsigned short* dstT = Ct + ((long)batch << 22);
#pragma unroll
    for (int i = 0; i < 4; ++i)
#pragma unroll
      for (int j = 0; j < 2; ++j) {
        u16x4 o;
#pragma unroll
        for (int r = 0; r < 4; ++r) o[r] = f2b_u(silu_f(acc[i][j][r]));
        *(u16x4*)(dstT + (long)(n0 + wn + (j << 4) + l16) * 8192 + s0 + (i << 4) + rq) = o;
      }
  }

  if (mode == 1) {
    // acc2: row = ch (rq+r), col = seq (l16)
#pragma unroll
    for (int ci = 0; ci < 2; ++ci) {
      float bv2[4];
#pragma unroll
      for (int r = 0; r < 4; ++r) bv2[r] = bias[n0 + wn + (ci << 4) + rq + r];
#pragma unroll
      for (int sj = 0; sj < 4; ++sj)
#pragma unroll
        for (int r = 0; r < 4; ++r) acc2[ci][sj][r] += bv2[r];
    }
    if (n0 + wn < 64) {  // rope: ch pairs are (r, r+1) within the lane — no shuffle
#pragma unroll
      for (int ci = 0; ci < 2; ++ci)
#pragma unroll
        for (int sj = 0; sj < 4; ++sj) {
          int pos = s0 + (sj << 4) + l16;
          const float* tb = TBL + ((long)pos << 6);
#pragma unroll
          for (int rp = 0; rp < 4; rp += 2) {
            int ip = (wn + (ci << 4) + rq + rp) >> 1;
            float sn = tb[ip << 1], cs = tb[(ip << 1) + 1];
            float v0 = acc2[ci][sj][rp], v1 = acc2[ci][sj][rp + 1];
            acc2[ci][sj][rp] = v0 * cs - sn * v1;
            acc2[ci][sj][rp + 1] = v1 * cs + sn * v0;
          }
        }
    }
    unsigned short* dstN = Kn + ((long)batch << 22);
#pragma unroll
    for (int ci = 0; ci < 2; ++ci)
#pragma unroll
      for (int sj = 0; sj < 4; ++sj) {
        u16x4 o;
#pragma unroll
        for (int r = 0; r < 4; ++r) o[r] = f2b_u(silu_f(acc2[ci][sj][r]));
        int seq = s0 + (sj << 4) + l16;
        *(u16x4*)(dstN + (long)seq * 512 + n0 + wn + (ci << 4) + rq) = o;
      }
  }
}

// ---------- QtV: P[z][gm][gn] = sum over K-chunk z&7 of V'[n,e] Q'[n,d] ----------
// split-K=8, DETERMINISTIC: each block plain-stores its own 128x128 tile into
// partial buffer P[z] (no atomics). Prefetch-distance-1 loop.
__global__ __launch_bounds__(256) void gemm_qtv(
    const unsigned short* __restrict__ A, const unsigned short* __restrict__ B,
    float* __restrict__ P) {
  __shared__ __align__(16) unsigned short smem[18432];
  unsigned short(*sA)[72] = (unsigned short(*)[72])smem;
  unsigned short(*sB)[72] = (unsigned short(*)[72])(smem + 9216);

  const int blk = blockIdx.x;
  const int low3 = blk & 7, hi = blk >> 3;
  const int m = ((low3 & 1) << 1) | (hi & 1);
  const int n = (low3 & 2) | ((hi >> 1) & 1);
  const int z = ((hi >> 2) << 1) | (low3 >> 2);  // 0..31
  const int batch = z >> 3, kc = z & 7;          // K-chunk 1024
  const unsigned short* A0 = A + (long)batch * 4194304 + (long)kc * 1024;
  const unsigned short* B0 = B + (long)batch * 4194304 + (long)kc * 1024;
  const int m0 = m << 7, n0 = n << 7;
  const int tid = threadIdx.x;
  const int lane = tid & 63, wave = tid >> 6;
  const int wm = (wave & 1) << 6, wn = (wave >> 1) << 6;
  const int l16 = lane & 15, q8 = (lane >> 4) << 3;

  f32x4 acc[4][4] = {};

  u16x8 ra[4], rb[4];
#pragma unroll
  for (int i = 0; i < 4; ++i) {
    int c = tid + (i << 8);
    int row = c >> 3, col = (c & 7) << 3;
    ra[i] = *(const u16x8*)(A0 + (long)(m0 + row) * 8192 + col);
    rb[i] = *(const u16x8*)(B0 + (long)(n0 + row) * 8192 + col);
  }

  for (int kt = 0; kt < 1024; kt += 64) {
    __syncthreads();
#pragma unroll
    for (int i = 0; i < 4; ++i) {
      int c = tid + (i << 8);
      int row = c >> 3, col = (c & 7) << 3;
      *(u16x8*)&sA[row][col] = ra[i];
      *(u16x8*)&sB[row][col] = rb[i];
    }
    __syncthreads();
    if (kt < 960) {  // prefetch next k-tile, hidden under MFMAs
#pragma unroll
      for (int i = 0; i < 4; ++i) {
        int c = tid + (i << 8);
        int row = c >> 3, col = (c & 7) << 3;
        ra[i] = *(const u16x8*)(A0 + (long)(m0 + row) * 8192 + kt + 64 + col);
        rb[i] = *(const u16x8*)(B0 + (long)(n0 + row) * 8192 + kt + 64 + col);
      }
    }
#pragma unroll
    for (int kk = 0; kk < 2; ++kk) {
      bf16x8 af[4], bfv[4];
#pragma unroll
      for (int i = 0; i < 4; ++i) {
        af[i] = *(const bf16x8*)&sA[wm + (i << 4) + l16][(kk << 5) + q8];
        bfv[i] = *(const bf16x8*)&sB[wn + (i << 4) + l16][(kk << 5) + q8];
      }
#pragma unroll
      for (int i = 0; i < 4; ++i)
#pragma unroll
        for (int j = 0; j < 4; ++j)
          acc[i][j] = __builtin_amdgcn_mfma_f32_16x16x32_bf16(af[i], bfv[j], acc[i][j], 0, 0, 0);
    }
  }

  const int rq = (lane >> 4) << 2;
  float* P0 = P + ((long)z << 18);  // per-(batch,kc) 512x512 partial
#pragma unroll
  for (int i = 0; i < 4; ++i)
#pragma unroll
    for (int j = 0; j < 4; ++j)
#pragma unroll
      for (int r = 0; r < 4; ++r) {
        int gm = m0 + wm + (i << 4) + rq + r;
        int gn = n0 + wn + (j << 4) + l16;
        P0[(long)gm * 512 + gn] = acc[i][j][r];
      }
}

// ---------- deterministic reduction of 8 K-chunk partials -> C2f ----------
__global__ __launch_bounds__(256) void reduce8(const float* __restrict__ P,
                                               float* __restrict__ C2f) {
  int i = (blockIdx.x * 256 + threadIdx.x) * 4;  // grid 1024 -> 1,048,576 floats
  int b = i >> 18, off = i & 262143;
  const float* p = P + ((long)(b << 3) << 18) + off;
  f32x4 s = *(const f32x4*)p;
#pragma unroll
  for (int kc = 1; kc < 8; ++kc) {
    f32x4 v = *(const f32x4*)(p + ((long)kc << 18));
    s += v;
  }
  *(f32x4*)(C2f + i) = s;
}

// ---------- per-(batch,d) column mean of C2f[b][e][d] over e ----------
__global__ __launch_bounds__(64) void colmean(const float* __restrict__ C, float* __restrict__ Cd) {
  const int bd = blockIdx.x;
  const int b = bd >> 9, d = bd & 511;
  const float* p = C + ((long)b << 18) + d;
  float s = 0.f;
  for (int e = threadIdx.x; e < 512; e += 64) s += p[(long)e << 9];
  s += __shfl_xor(s, 1);
  s += __shfl_xor(s, 2);
  s += __shfl_xor(s, 4);
  s += __shfl_xor(s, 8);
  s += __shfl_xor(s, 16);
  s += __shfl_xor(s, 32);
  if (threadIdx.x == 0) Cd[bd] = s * (1.f / 512.f);
}

// ---------- centered fp32 -> bf16 + scalar passthrough ----------
__global__ __launch_bounds__(256) void cvt_center(const float* __restrict__ in,
                                                  const float* __restrict__ Cd,
                                                  unsigned short* __restrict__ out,
                                                  const float* __restrict__ Sh,
                                                  const float* __restrict__ Sc,
                                                  float* __restrict__ outp) {
  int i = (blockIdx.x * 256 + threadIdx.x) * 4;
  f32x4 x = *(const f32x4*)(in + i);
  int b = i >> 18, d = i & 511;
  f32x4 c = *(const f32x4*)(Cd + (b << 9) + d);
  u16x4 o;
#pragma unroll
  for (int j = 0; j < 4; ++j) o[j] = f2b_u(x[j] - c[j]);
  *(u16x4*)(out + i) = o;
  if (blockIdx.x == 0 && threadIdx.x == 0) {
    outp[16777216] = Sh[0];
    outp[16777217] = Sc[0];
  }
}

// ---------- GEMM4 + fused GroupNorm (prefetch-distance-1 loop) ----------
__global__ __launch_bounds__(256) void gemm4_gn(
    const unsigned short* __restrict__ A, const unsigned short* __restrict__ B,
    const float* __restrict__ gnw, const float* __restrict__ gnb,
    float* __restrict__ out) {
  __shared__ __align__(16) unsigned short smem[18432];
  unsigned short(*sA)[72] = (unsigned short(*)[72])smem;
  unsigned short(*sB)[72] = (unsigned short(*)[72])(smem + 9216);

  const int blk = blockIdx.x;
  const int mt = blk & 255, n = blk >> 8;
  const int batch = mt >> 6;
  const int m0 = (mt & 63) << 7, n0 = n << 7;
  const unsigned short* A0 = A + (long)batch * 4194304;
  const unsigned short* B0 = B + (long)batch * 262144;
  const int tid = threadIdx.x;
  const int lane = tid & 63, wave = tid >> 6;
  const int wm = (wave & 1) << 6, wn = (wave >> 1) << 6;
  const int l16 = lane & 15, q8 = (lane >> 4) << 3;

  f32x4 acc[4][4] = {};

  u16x8 ra[4], rb[4];
#pragma unroll
  for (int i = 0; i < 4; ++i) {
    int c = tid + (i << 8);
    int row = c >> 3, col = (c & 7) << 3;
    ra[i] = *(const u16x8*)(A0 + (long)(m0 + row) * 512 + col);
    rb[i] = *(const u16x8*)(B0 + (long)(n0 + row) * 512 + col);
  }

  for (int kt = 0; kt < 512; kt += 64) {
    __syncthreads();
#pragma unroll
    for (int i = 0; i < 4; ++i) {
      int c = tid + (i << 8);
      int row = c >> 3, col = (c & 7) << 3;
      *(u16x8*)&sA[row][col] = ra[i];
      *(u16x8*)&sB[row][col] = rb[i];
    }
    __syncthreads();
    if (kt < 448) {  // prefetch next k-tile, hidden under MFMAs
#pragma unroll
      for (int i = 0; i < 4; ++i) {
        int c = tid + (i << 8);
        int row = c >> 3, col = (c & 7) << 3;
        ra[i] = *(const u16x8*)(A0 + (long)(m0 + row) * 512 + kt + 64 + col);
        rb[i] = *(const u16x8*)(B0 + (long)(n0 + row) * 512 + kt + 64 + col);
      }
    }
#pragma unroll
    for (int kk = 0; kk < 2; ++kk) {
      bf16x8 af[4], bfv[4];
#pragma unroll
      for (int i = 0; i < 4; ++i) {
        af[i] = *(const bf16x8*)&sA[wm + (i << 4) + l16][(kk << 5) + q8];
        bfv[i] = *(const bf16x8*)&sB[wn + (i << 4) + l16][(kk << 5) + q8];
      }
#pragma unroll
      for (int i = 0; i < 4; ++i)
#pragma unroll
        for (int j = 0; j < 4; ++j)
          acc[i][j] = __builtin_amdgcn_mfma_f32_16x16x32_bf16(af[i], bfv[j], acc[i][j], 0, 0, 0);
    }
  }

  const int rq = (lane >> 4) << 2;
  float wv[4], bb[4];
#pragma unroll
  for (int j = 0; j < 4; ++j) {
    int gn = n0 + wn + (j << 4) + l16;
    wv[j] = gnw[gn];
    bb[j] = gnb[gn];
  }
  float* obase = out + (long)batch * 4194304;
#pragma unroll
  for (int i = 0; i < 4; ++i) {
    float mean[4], inv[4];
#pragma unroll
    for (int r = 0; r < 4; ++r) {
      float s = acc[i][0][r] + acc[i][1][r] + acc[i][2][r] + acc[i][3][r];
      s += __shfl_xor(s, 1);
      s += __shfl_xor(s, 2);
      s += __shfl_xor(s, 4);
      s += __shfl_xor(s, 8);
      mean[r] = s * (1.f / 64.f);
      float sq = 0.f;
#pragma unroll
      for (int j = 0; j < 4; ++j) {
        float d = acc[i][j][r] - mean[r];
        sq += d * d;
      }
      sq += __shfl_xor(sq, 1);
      sq += __shfl_xor(sq, 2);
      sq += __shfl_xor(sq, 4);
      sq += __shfl_xor(sq, 8);
      inv[r] = rsqrtf(sq * (1.f / 64.f) + 1e-6f);
    }
#pragma unroll
    for (int j = 0; j < 4; ++j) {
      int gn = n0 + wn + (j << 4) + l16;
#pragma unroll
      for (int r = 0; r < 4; ++r) {
        int gm = m0 + wm + (i << 4) + rq + r;
        obase[(long)gm * 512 + gn] = (acc[i][j][r] - mean[r]) * inv[r] * wv[j] + bb[j];
      }
    }
  }
}

// ---------- launch ----------
extern "C" void kernel_launch(void* const* d_in, const int* in_sizes, int n_in,
                              void* d_out, int out_size, void* d_ws, size_t ws_size,
                              hipStream_t stream) {
  const float* Xq = (const float*)d_in[0];
  const float* Xkv = (const float*)d_in[1];
  const float* Sh = (const float*)d_in[2];
  const float* Sc = (const float*)d_in[3];
  const float* Wq = (const float*)d_in[4];
  const float* bq = (const float*)d_in[5];
  // d_in[6]=Wk, d_in[7]=bk : dead code in reference
  const float* Wv = (const float*)d_in[8];
  const float* bv = (const float*)d_in[9];
  const float* gnw = (const float*)d_in[10];
  const float* gnb = (const float*)d_in[11];

  char* ws = (char*)d_ws;
  // layout (bytes), peak = 106,962,944 (proven available):
  unsigned short* QT = (unsigned short*)(ws);                // [4][512][8192] bf16
  unsigned short* VT = (unsigned short*)(ws + 33554432L);
  unsigned short* Kn = (unsigned short*)(ws + 67108864L);    // [4][8192][512] bf16
  float* C2f = (float*)(ws + 100663296L);                    // [4][512][512] f32 = 4 MB
  unsigned short* C2c = (unsigned short*)(ws + 104857600L);  // 2 MB
  float* Cd = (float*)(ws + 106954752L);                     // 8 KB
  // proj-phase overlays in the C2f region (dead until reduce8):
  unsigned short* Wqb = (unsigned short*)(ws + 100663296L);             // 0.5 MB
  unsigned short* Wvb = (unsigned short*)(ws + 100663296L + 524288L);   // 0.5 MB
  float* TBL = (float*)(ws + 100663296L + 1048576L);                    // 2 MB
  float* outp = (float*)d_out;
  // split-K partials: 32 MB staged in d_out (dead until gemm4_gn overwrites it)
  float* Pp = (float*)d_out;

  if (ws_size < 106962944UL) return;

  // 0: weights fp32 -> bf16 + rope table, one launch
  setup_k<<<1536, 256, 0, stream>>>(Wq, Wv, Wqb, Wvb, TBL);

  // 1: BOTH projections, one launch (mode = blockIdx.x & 1) — co-resident hetero blocks
  proj6<<<2048, 512, 0, stream>>>(Xq, Xkv, Wqb, Wvb, bq, bv, QT, VT, Kn, TBL);

  // 2: QtV^T partials (split-K=8, plain stores — deterministic)
  gemm_qtv<<<512, 256, 0, stream>>>(VT, QT, Pp);

  // 2a: deterministic fixed-order reduction of the 8 partials
  reduce8<<<1024, 256, 0, stream>>>(Pp, C2f);

  // 2b: center per (b,d), round to bf16; scalar passthrough
  colmean<<<2048, 64, 0, stream>>>(C2f, Cd);
  cvt_center<<<1024, 256, 0, stream>>>(C2f, Cd, C2c, Sh, Sc, outp);

  // 3: out = GroupNorm( K' @ (QtV - Cd) ) fused — overwrites the partial region
  gemm4_gn<<<1024, 256, 0, stream>>>(Kn, C2c, gnw, gnb, outp);
}